// Round 3
// baseline (446.923 us; speedup 1.0000x reference)
//
#include <hip/hip_runtime.h>
#include <hip/hip_bf16.h>

// AgentEncoder: B=256, A=512, T=21, DIM=128, SC=6, NHEAD=4, HD=32
// Stage1 on MFMA (mfma_f32_16x16x32_bf16), BARRIER-FREE:
//  - each wave owns 4 agents end-to-end (feature->conv1->conv2->conv3->store);
//    all LDS per-wave, same-wave RAW via lgkmcnt => zero __syncthreads.
//  - column map n=4p+ag keeps all conv LDS reads at exact 2-way bank alias.
//  - garbage tile columns clamp-read (pg=min(p,PMAX), lands on real/zero rows)
//    and are write-masked; weights K-padded with zeros.
//  - runtime g_dtype branch inside kernels (uniform) => no dummy dispatches:
//    4 launches total (detect, prep, stage1, stage2).
// (Round 3 resubmit: round-2 run died to container/infra failure, not kernel.)

#define BB 256
#define AAG 512
#define TT 21
#define NAG (BB * AAG)

typedef __hip_bfloat16 bf16;
typedef __attribute__((ext_vector_type(8))) short s8v;   // 8 bf16 = 4 VGPR
typedef __attribute__((ext_vector_type(4))) float f4v;   // mfma acc

__device__ int g_dtype;        // 1 = bf16 inputs, 0 = f32 inputs
__device__ int g_mask_mode;    // 0=i32, 1=u8, 2=f32, 3=bf16
__device__ __align__(16) short g_w1p[32 * 64];    // [oc][k=tap*16+ic], pad0
__device__ __align__(16) short g_w2p[64 * 96];    // [oc][k=tap*32+ic]
__device__ __align__(16) short g_w3p[128 * 192];  // [oc][k=tap*64+ic]
__device__ __align__(16) float g_b1[32];
__device__ __align__(16) float g_b2[64];
__device__ __align__(16) float g_b3[128];

template <int DT>
__device__ __forceinline__ float ldf(const void* p, long i) {
    if (DT) return __bfloat162float(((const bf16*)p)[i]);
    return ((const float*)p)[i];
}
template <int DT>
__device__ __forceinline__ void stf(void* p, long i, float v) {
    if (DT) ((bf16*)p)[i] = __float2bfloat16(v);
    else    ((float*)p)[i] = v;
}
__device__ __forceinline__ unsigned short f2bu(float x) {
    bf16 b = __float2bfloat16(x);
    union { bf16 b; unsigned short u; } cv; cv.b = b; return cv.u;
}
__device__ __forceinline__ float bu2f(unsigned short u) {
    union { unsigned int i; float f; } cv; cv.i = ((unsigned int)u) << 16; return cv.f;
}
template <int DT>
__device__ __forceinline__ float2 ldf2(const void* p, long i) {  // i even
    if (DT) {
        unsigned int u = *(const unsigned int*)((const bf16*)p + i);
        return make_float2(bu2f((unsigned short)(u & 0xffffu)),
                           bu2f((unsigned short)(u >> 16)));
    }
    return *(const float2*)((const float*)p + i);
}
__device__ __forceinline__ bool mask_at(const void* p, long i, int mode) {
    if (mode == 0) return ((const int*)p)[i] != 0;
    if (mode == 1) return ((const unsigned char*)p)[i] != 0;
    if (mode == 2) return ((const float*)p)[i] != 0.f;
    return (((const unsigned short*)p)[i] & 0x7fff) != 0;
}

// ---------------- dtype + mask detection (1 block) ----------------
__global__ void detect_kernel(const unsigned int* __restrict__ pw,
                              const unsigned char* __restrict__ m) {
    __shared__ int cls[4];
    __shared__ int mv;
    __shared__ int good;
    int tid = threadIdx.x;
    if (tid < 4) cls[tid] = 0;
    if (tid == 0) { mv = 0; good = 0; }
    __syncthreads();
    int g = 0;
    for (int i = tid; i < 1024; i += 256) {
        unsigned int w = pw[i];
        unsigned int h0 = w & 0xffffu, h1 = w >> 16;
        unsigned int e0 = (h0 >> 7) & 0xff, e1 = (h1 >> 7) & 0xff;
        if (h0 == 0 || (e0 >= 90 && e0 <= 160)) g++;
        if (h1 == 0 || (e1 >= 90 && e1 <= 160)) g++;
    }
    atomicAdd(&good, g);
    int l0 = 0, l1 = 0, l2 = 0, l3 = 0, lm = 0;
    for (int i = tid; i < 4096; i += 256) {
        int v = m[i];
        if (v) {
            switch (i & 3) { case 0: l0 = 1; break; case 1: l1 = 1; break;
                             case 2: l2 = 1; break; default: l3 = 1; }
            if (v > lm) lm = v;
        }
    }
    if (l0) atomicOr(&cls[0], 1);
    if (l1) atomicOr(&cls[1], 1);
    if (l2) atomicOr(&cls[2], 1);
    if (l3) atomicOr(&cls[3], 1);
    atomicMax(&mv, lm);
    __syncthreads();
    if (tid == 0) {
        g_dtype = (good >= 1740) ? 1 : 0;
        int mode;
        if (!cls[1] && !cls[2] && !cls[3]) mode = 0;
        else if (!cls[0] && !cls[1])       mode = 2;
        else if (mv <= 1)                  mode = 1;
        else                               mode = 3;
        g_mask_mode = mode;
    }
}

// ---------------- weight pad/transpose/cast ----------------
template <int DT>
__device__ __forceinline__ void prep_body(const void* w1, const void* b1,
                                          const void* w2, const void* b2,
                                          const void* w3, const void* b3) {
    int tid = blockIdx.x * blockDim.x + threadIdx.x;
    int nt = gridDim.x * blockDim.x;
    for (int i = tid; i < 32 * 64; i += nt) {
        int oc = i >> 6, k = i & 63, tap = k >> 4, ic = k & 15;
        float v = (tap < 3 && ic < 9) ? ldf<DT>(w1, oc * 27 + ic * 3 + tap) : 0.f;
        g_w1p[i] = (short)f2bu(v);
    }
    for (int i = tid; i < 64 * 96; i += nt) {
        int oc = i / 96, k = i % 96, tap = k >> 5, ic = k & 31;
        g_w2p[i] = (short)f2bu(ldf<DT>(w2, oc * 96 + ic * 3 + tap));
    }
    for (int i = tid; i < 128 * 192; i += nt) {
        int oc = i / 192, k = i % 192, tap = k >> 6, ic = k & 63;
        g_w3p[i] = (short)f2bu(ldf<DT>(w3, oc * 192 + ic * 3 + tap));
    }
    for (int i = tid; i < 32; i += nt) g_b1[i] = ldf<DT>(b1, i);
    for (int i = tid; i < 64; i += nt) g_b2[i] = ldf<DT>(b2, i);
    for (int i = tid; i < 128; i += nt) g_b3[i] = ldf<DT>(b3, i);
}

__global__ void prep_weights_kernel(const void* __restrict__ w1, const void* __restrict__ b1,
                                    const void* __restrict__ w2, const void* __restrict__ b2,
                                    const void* __restrict__ w3, const void* __restrict__ b3) {
    if (g_dtype) prep_body<1>(w1, b1, w2, b2, w3, b3);
    else         prep_body<0>(w1, b1, w2, b2, w3, b3);
}

// ---------------- stage 1: 16 agents/block, 4 waves, 4 agents/wave ----------------
// LDS (shorts). Region A: feat [16][FEAT_AS] (per-wave 4 agents), aliased by h2.
// Region B: h1 [16][H1_AS], aliased by c3 ([ag][p*C3_RS], agent stride H1_AS).
// Agent strides == +-4 banks (mod 32); row strides chosen for 2-way max alias.
#define FEAT_RS 24     // rows t=0..21 (20,21 zero); 48 B
#define FEAT_AS 568    // 1136 B == -4 banks (mod 32)
#define H1_RS 40       // rows 0..10 (10 zero); 80 B
#define H1_AS 440      // 880 B == -4 banks
#define H2_RS 72       // rows 0..6 (0,6 zero); 144 B == +4 banks
#define H2_AS 504      // 1008 B == -4 banks
#define C3_RS 144      // 288 B == +8 banks (2-way with ag over n=4p+ag)
#define OFF_H1 9088    // shorts = 16*FEAT_AS
#define OFF_VALID 32256 // bytes = (OFF_H1 + 16*H1_AS)*2
#define SMEM_BYTES 32320 // -> 32768 alloc => 5 blocks/CU

#define MFMA16(a, b, c) __builtin_amdgcn_mfma_f32_16x16x32_bf16((a), (b), (c), 0, 0, 0)

__device__ __forceinline__ uint2 pack_relu(f4v acc, f4v bia) {
    unsigned int lo = f2bu(fmaxf(acc[0] + bia[0], 0.f)) | ((unsigned int)f2bu(fmaxf(acc[1] + bia[1], 0.f)) << 16);
    unsigned int hi = f2bu(fmaxf(acc[2] + bia[2], 0.f)) | ((unsigned int)f2bu(fmaxf(acc[3] + bia[3], 0.f)) << 16);
    return make_uint2(lo, hi);
}

template <int DT>
__device__ __forceinline__ void stage1_body(
    const void* pos, const void* heading, const void* vel, const void* shp,
    const void* vmask, const int* category, const void* type_emb, void* out,
    char* smem) {
    const int tid = threadIdx.x;
    const int wave = tid >> 6, lane = tid & 63;
    const int col = lane & 15, quad = lane >> 4;
    const long agent0 = (long)blockIdx.x * 16;
    const int mode = g_mask_mode;

    int* s_valid = (int*)(smem + OFF_VALID);
    // per-wave regions (4 agents each)
    short* feat = (short*)smem + wave * 4 * FEAT_AS;
    short* h1   = (short*)smem + OFF_H1 + wave * 4 * H1_AS;
    short* h2   = feat;   // region A reuse (feat dead after this wave's conv1)
    short* c3   = h1;     // region B reuse (h1 dead after this wave's conv2)

    // ---- init: valid flags + h1 zero row 10 (per-wave, no barrier needed) ----
    if (lane < 4) s_valid[wave * 4 + lane] = 0;
    {
        unsigned int* h1u = (unsigned int*)h1;
        h1u[(lane >> 4) * 220 + 200 + (lane & 15)] = 0;
    }

    // ---- feature build: 4 agents x 22 rows (t=20,21 zero pads) ----
    for (int idx = lane; idx < 88; idx += 64) {
        int ag = idx / 22, t = idx % 22;
        short* row = feat + ag * FEAT_AS + t * FEAT_RS;
        long base = (agent0 + wave * 4 + ag) * TT + t;
        if (t >= 20) {
            *(uint4*)row = make_uint4(0, 0, 0, 0);
            *(uint4*)(row + 8) = make_uint4(0, 0, 0, 0);
            if (t == 20 && mask_at(vmask, base, mode)) atomicOr(&s_valid[wave * 4 + ag], 1);
        } else {
            bool vmt = mask_at(vmask, base, mode);
            if (vmt) atomicOr(&s_valid[wave * 4 + ag], 1);
            bool m2 = vmt && mask_at(vmask, base + 1, mode);
            float2 pa = ldf2<DT>(pos, base * 2), pb = ldf2<DT>(pos, base * 2 + 2);
            float2 va = ldf2<DT>(vel, base * 2), vb = ldf2<DT>(vel, base * 2 + 2);
            float hh0 = ldf<DT>(heading, base), hh1 = ldf<DT>(heading, base + 1);
            float2 sv = ldf2<DT>(shp, base * 2 + 2);
            float dh = m2 ? (hh1 - hh0) : 0.f;      // masked: cos=1, sin=0 (ref)
            float sn, cn;
            __sincosf(dh, &sn, &cn);
            unsigned int p0 = f2bu(m2 ? pb.x - pa.x : 0.f) | ((unsigned int)f2bu(m2 ? pb.y - pa.y : 0.f) << 16);
            unsigned int p1 = f2bu(m2 ? vb.x - va.x : 0.f) | ((unsigned int)f2bu(m2 ? vb.y - va.y : 0.f) << 16);
            unsigned int p2 = f2bu(cn) | ((unsigned int)f2bu(sn) << 16);
            unsigned int p3 = f2bu(sv.x) | ((unsigned int)f2bu(sv.y) << 16);
            unsigned int p4 = (unsigned int)f2bu(m2 ? 1.f : 0.f);
            *(uint4*)row = make_uint4(p0, p1, p2, p3);
            *(uint4*)(row + 8) = make_uint4(p4, 0, 0, 0);
        }
    }

    // ---- conv1: M=32 (2 Mt), K=64 (taps 0..2 + zero tap3), N=4ag x 10p -> 3 tiles ----
    {
        s8v a00 = *(const s8v*)(g_w1p + col * 64 + quad * 8);
        s8v a01 = *(const s8v*)(g_w1p + col * 64 + 32 + quad * 8);
        s8v a10 = *(const s8v*)(g_w1p + (16 + col) * 64 + quad * 8);
        s8v a11 = *(const s8v*)(g_w1p + (16 + col) * 64 + 32 + quad * 8);
        f4v bia0 = *(const f4v*)(g_b1 + quad * 4);
        f4v bia1 = *(const f4v*)(g_b1 + 16 + quad * 4);
        int k0 = quad * 8, k1 = 32 + quad * 8;
        int tap0 = k0 >> 4, ic0 = k0 & 15;
        int tap1 = k1 >> 4, ic1 = k1 & 15;
#pragma unroll
        for (int nt = 0; nt < 3; nt++) {
            int n = nt * 16 + col;
            int p = n >> 2, ag = n & 3;
            int pg = p > 9 ? 9 : p;                 // clamp garbage cols (rows <= 21)
            const short* bb = feat + ag * FEAT_AS + 2 * pg * FEAT_RS;
            s8v b0 = *(const s8v*)(bb + tap0 * FEAT_RS + ic0);
            s8v b1 = *(const s8v*)(bb + tap1 * FEAT_RS + ic1);
            f4v acc0 = {0.f, 0.f, 0.f, 0.f}, acc1 = {0.f, 0.f, 0.f, 0.f};
            acc0 = MFMA16(a00, b0, acc0); acc0 = MFMA16(a01, b1, acc0);
            acc1 = MFMA16(a10, b0, acc1); acc1 = MFMA16(a11, b1, acc1);
            if (p < 10) {
                short* wr = h1 + ag * H1_AS + p * H1_RS + quad * 4;
                *(uint2*)wr = pack_relu(acc0, bia0);
                *(uint2*)(wr + 16) = pack_relu(acc1, bia1);
            }
        }
    }

    // ---- h2 zero pad rows 0 & 6 (region A: this wave's feat is dead now) ----
    {
        unsigned int* h2u = (unsigned int*)h2;
#pragma unroll
        for (int j = 0; j < 4; j++)
            h2u[j * 252 + (lane >> 5) * 216 + (lane & 31)] = 0;
    }

    // ---- conv2: M=64 (4 Mt), K=96, N=4ag x 5p -> 2 tiles (tile1: p=4 + garbage) ----
    {
        int p0 = col >> 2, ag0 = col & 3;                 // tile 0: p 0..3
        int n1 = 16 + col;
        int p1 = n1 >> 2, ag1 = n1 & 3;                   // tile 1: p 4..7
        int pg1 = p1 > 4 ? 4 : p1;
#pragma unroll
        for (int Mt = 0; Mt < 4; Mt++) {
            s8v a0 = *(const s8v*)(g_w2p + (Mt * 16 + col) * 96 + quad * 8);
            s8v a1 = *(const s8v*)(g_w2p + (Mt * 16 + col) * 96 + 32 + quad * 8);
            s8v a2 = *(const s8v*)(g_w2p + (Mt * 16 + col) * 96 + 64 + quad * 8);
            f4v bia = *(const f4v*)(g_b2 + Mt * 16 + quad * 4);
            {
                const short* bb = h1 + ag0 * H1_AS + 2 * p0 * H1_RS + quad * 8;
                f4v acc = {0.f, 0.f, 0.f, 0.f};
                acc = MFMA16(a0, *(const s8v*)(bb), acc);
                acc = MFMA16(a1, *(const s8v*)(bb + H1_RS), acc);
                acc = MFMA16(a2, *(const s8v*)(bb + 2 * H1_RS), acc);
                *(uint2*)(h2 + ag0 * H2_AS + (p0 + 1) * H2_RS + Mt * 16 + quad * 4) =
                    pack_relu(acc, bia);
            }
            {
                const short* bb = h1 + ag1 * H1_AS + 2 * pg1 * H1_RS + quad * 8;
                f4v acc = {0.f, 0.f, 0.f, 0.f};
                acc = MFMA16(a0, *(const s8v*)(bb), acc);
                acc = MFMA16(a1, *(const s8v*)(bb + H1_RS), acc);
                acc = MFMA16(a2, *(const s8v*)(bb + 2 * H1_RS), acc);
                if (p1 == 4)
                    *(uint2*)(h2 + ag1 * H2_AS + (p1 + 1) * H2_RS + Mt * 16 + quad * 4) =
                        pack_relu(acc, bia);
            }
        }
    }

    // ---- conv3: M=128 (8 Mt), K=192 (6 slices), N=4ag x 3p -> 1 tile ----
    {
        int p = col >> 2, ag = col & 3;
        int pg = p > 2 ? 2 : p;
        s8v b[6];
#pragma unroll
        for (int ks = 0; ks < 6; ks++) {
            int kg = ks * 32 + quad * 8;
            int tap = kg >> 6, ic = kg & 63;
            b[ks] = *(const s8v*)(h2 + ag * H2_AS + (2 * pg + tap) * H2_RS + ic);
        }
#pragma unroll
        for (int Mt = 0; Mt < 8; Mt++) {
            f4v acc = {0.f, 0.f, 0.f, 0.f};
#pragma unroll
            for (int ks = 0; ks < 6; ks++) {
                s8v a = *(const s8v*)(g_w3p + (Mt * 16 + col) * 192 + ks * 32 + quad * 8);
                acc = MFMA16(a, b[ks], acc);
            }
            if (p < 3) {
                f4v bia = *(const f4v*)(g_b3 + Mt * 16 + quad * 4);
                *(uint2*)(c3 + ag * H1_AS + p * C3_RS + Mt * 16 + quad * 4) =
                    pack_relu(acc, bia);
            }
        }
    }

    // ---- epilogue (per-wave): mean over 3 p, valid mask, + type_emb ----
    {
        int ag = lane >> 4;                 // 0..3 within wave
        int ocg = (lane & 15) * 8;
        const short* cb = c3 + ag * H1_AS;
        s8v x0 = *(const s8v*)(cb + ocg);
        s8v x1 = *(const s8v*)(cb + C3_RS + ocg);
        s8v x2 = *(const s8v*)(cb + 2 * C3_RS + ocg);
        int valid = s_valid[wave * 4 + ag];
        long agl = agent0 + wave * 4 + ag;
        int cat = category[agl];
        float vals[8];
#pragma unroll
        for (int j = 0; j < 8; j++) {
            float m = (bu2f((unsigned short)x0[j]) + bu2f((unsigned short)x1[j]) +
                       bu2f((unsigned short)x2[j])) * (1.f / 3.f);
            vals[j] = valid ? m : 0.f;
        }
        if (DT) {
            s8v te = *(const s8v*)((const bf16*)type_emb + (long)cat * 128 + ocg);
            s8v o;
#pragma unroll
            for (int j = 0; j < 8; j++)
                o[j] = (short)f2bu(vals[j] + bu2f((unsigned short)te[j]));
            *(s8v*)((bf16*)out + agl * 128 + ocg) = o;
        } else {
            const float4* tep = (const float4*)((const float*)type_emb + (long)cat * 128 + ocg);
            float4 t0 = tep[0], t1 = tep[1];
            float4 o0 = make_float4(vals[0] + t0.x, vals[1] + t0.y, vals[2] + t0.z, vals[3] + t0.w);
            float4 o1 = make_float4(vals[4] + t1.x, vals[5] + t1.y, vals[6] + t1.z, vals[7] + t1.w);
            float4* op = (float4*)((float*)out + agl * 128 + ocg);
            op[0] = o0; op[1] = o1;
        }
    }
}

__global__ __launch_bounds__(256) void stage1_kernel(
    const void* __restrict__ pos, const void* __restrict__ heading,
    const void* __restrict__ vel, const void* __restrict__ shp,
    const void* __restrict__ vmask, const int* __restrict__ category,
    const void* __restrict__ type_emb, void* __restrict__ out) {
    __shared__ __align__(16) char smem[SMEM_BYTES];
    if (g_dtype) stage1_body<1>(pos, heading, vel, shp, vmask, category, type_emb, out, smem);
    else         stage1_body<0>(pos, heading, vel, shp, vmask, category, type_emb, out, smem);
}

// ---------------- stage 2: ego cross-attention, overwrites row a=0 ----------------
// smem layout (floats): xe[6*128]@0, qu[128]@768, q[128]@896, k[6*128]@1024,
// v[6*128]@1792, att[24]@2560, o[128]@2584  (total 2712 floats)
template <int DT>
__device__ __forceinline__ void stage2_body(
    const void* cs, const int* category,
    const void* se_w, const void* se_b, const void* pe, const void* query,
    const void* ipw, const void* ipb, const void* opw, const void* opb,
    const void* type_emb, void* out, float* sm) {
    int b = blockIdx.x, d = threadIdx.x;
    float* s_xe = sm;
    float* s_qu = sm + 768;
    float* s_q  = sm + 896;
    float* s_k  = sm + 1024;
    float* s_v  = sm + 1792;
    float* s_att = sm + 2560;
    float* s_o  = sm + 2584;

    s_qu[d] = ldf<DT>(query, d);
#pragma unroll
    for (int s = 0; s < 6; s++) {
        float ego = ldf<DT>(cs, b * 6 + s);
        s_xe[s * 128 + d] = fmaf(ego, ldf<DT>(se_w, s * 128 + d),
                                 ldf<DT>(se_b, s * 128 + d) + ldf<DT>(pe, s * 128 + d));
    }
    __syncthreads();

    float accq = ldf<DT>(ipb, d);
    float bk = ldf<DT>(ipb, 128 + d), bv = ldf<DT>(ipb, 256 + d);
    float acck[6], accv[6];
#pragma unroll
    for (int s = 0; s < 6; s++) { acck[s] = bk; accv[s] = bv; }
    for (int e = 0; e < 128; e++) {
        float wqe = ldf<DT>(ipw, (long)d * 128 + e);
        accq = fmaf(s_qu[e], wqe, accq);
        float wke = ldf<DT>(ipw, (long)(128 + d) * 128 + e);
        float wve = ldf<DT>(ipw, (long)(256 + d) * 128 + e);
#pragma unroll
        for (int s = 0; s < 6; s++) {
            float xe = s_xe[s * 128 + e];
            acck[s] = fmaf(xe, wke, acck[s]);
            accv[s] = fmaf(xe, wve, accv[s]);
        }
    }
    s_q[d] = accq;
#pragma unroll
    for (int s = 0; s < 6; s++) { s_k[s * 128 + d] = acck[s]; s_v[s * 128 + d] = accv[s]; }
    __syncthreads();

    if (d < 4) {
        float sc[6];
        float mx = -1e30f;
#pragma unroll
        for (int s = 0; s < 6; s++) {
            float t = 0.f;
            for (int q = 0; q < 32; q++) t = fmaf(s_q[d * 32 + q], s_k[s * 128 + d * 32 + q], t);
            t *= 0.17677669529663687f;
            sc[s] = t;
            mx = fmaxf(mx, t);
        }
        float sum = 0.f;
#pragma unroll
        for (int s = 0; s < 6; s++) { sc[s] = expf(sc[s] - mx); sum += sc[s]; }
        float inv = 1.f / sum;
#pragma unroll
        for (int s = 0; s < 6; s++) s_att[d * 6 + s] = sc[s] * inv;
    }
    __syncthreads();

    {
        int h = d >> 5;
        float o = 0.f;
#pragma unroll
        for (int s = 0; s < 6; s++) o = fmaf(s_att[h * 6 + s], s_v[s * 128 + d], o);
        s_o[d] = o;
    }
    __syncthreads();

    float acc = ldf<DT>(opb, d);
    for (int e = 0; e < 128; e++) acc = fmaf(s_o[e], ldf<DT>(opw, (long)d * 128 + e), acc);
    int cat = category[(long)b * AAG];
    stf<DT>(out, (long)b * AAG * 128 + d, acc + ldf<DT>(type_emb, cat * 128 + d));
}

__global__ __launch_bounds__(128) void stage2_kernel(
    const void* __restrict__ cs, const int* __restrict__ category,
    const void* __restrict__ se_w, const void* __restrict__ se_b,
    const void* __restrict__ pe, const void* __restrict__ query,
    const void* __restrict__ ipw, const void* __restrict__ ipb,
    const void* __restrict__ opw, const void* __restrict__ opb,
    const void* __restrict__ type_emb, void* __restrict__ out) {
    __shared__ float sm[2712];
    if (g_dtype) stage2_body<1>(cs, category, se_w, se_b, pe, query, ipw, ipb, opw, opb, type_emb, out, sm);
    else         stage2_body<0>(cs, category, se_w, se_b, pe, query, ipw, ipb, opw, opb, type_emb, out, sm);
}

extern "C" void kernel_launch(void* const* d_in, const int* in_sizes, int n_in,
                              void* d_out, int out_size, void* d_ws, size_t ws_size,
                              hipStream_t stream) {
    const void* position      = d_in[0];
    const void* heading       = d_in[1];
    const void* velocity      = d_in[2];
    const void* shape         = d_in[3];
    const void* current_state = d_in[4];
    const int*  category      = (const int*)d_in[5];
    const void* valid_mask    = d_in[6];
    const void* conv1_w = d_in[7];
    const void* conv1_b = d_in[8];
    const void* conv2_w = d_in[9];
    const void* conv2_b = d_in[10];
    const void* conv3_w = d_in[11];
    const void* conv3_b = d_in[12];
    const void* se_w    = d_in[13];
    const void* se_b    = d_in[14];
    const void* pos_embed = d_in[15];
    const void* query     = d_in[16];
    const void* in_proj_w = d_in[17];
    const void* in_proj_b = d_in[18];
    const void* out_proj_w = d_in[19];
    const void* out_proj_b = d_in[20];
    const void* type_emb   = d_in[21];

    hipLaunchKernelGGL(detect_kernel, dim3(1), dim3(256), 0, stream,
                       (const unsigned int*)position, (const unsigned char*)valid_mask);

    hipLaunchKernelGGL(prep_weights_kernel, dim3(64), dim3(256), 0, stream,
                       conv1_w, conv1_b, conv2_w, conv2_b, conv3_w, conv3_b);

    hipLaunchKernelGGL(stage1_kernel, dim3(NAG / 16), dim3(256), 0, stream,
                       position, heading, velocity, shape, valid_mask, category, type_emb, d_out);

    hipLaunchKernelGGL(stage2_kernel, dim3(BB), dim3(128), 0, stream,
                       current_state, category, se_w, se_b, pos_embed, query,
                       in_proj_w, in_proj_b, out_proj_w, out_proj_b, type_emb, d_out);
}

// Round 4
// 300.734 us; speedup vs baseline: 1.4861x; 1.4861x over previous
//
#include <hip/hip_runtime.h>
#include <hip/hip_bf16.h>

// AgentEncoder: B=256, A=512, T=21, DIM=128, SC=6, NHEAD=4, HD=32
// Round 4: revert stage1 to the round-1 verified structure (131 us measured;
// round-3's barrier-free N-split destroyed weight-fragment reuse: post-mortem).
// New: 2 launches total.
//   Launch A (prep_kernel, 65 blocks): per-block inline dtype/mask detection
//     (no cross-block dep), weight pad/cast, block 64 pre-folds q@Wk -> g_wqk
//     (scores become a 4x128 projection; stage2 loses its K/Q paths).
//   Launch B (fused_kernel, 256+8192 blocks): blocks<256 run stage2 (softmax
//     fold: sum att = 1 -> o = bv + y_h @ Wv, vectorized 16B weight loads);
//     blocks>=256 run round-1 stage1, skipping agent-0 stores (stage2 owns them;
//     writes disjoint -> no ordering needed).

#define BB 256
#define AAG 512
#define TT 21
#define NAG (BB * AAG)

typedef __hip_bfloat16 bf16;
typedef __attribute__((ext_vector_type(8))) short s8v;   // 8 bf16 = 4 VGPR
typedef __attribute__((ext_vector_type(4))) float f4v;   // mfma acc

__device__ int g_dtype;        // 1 = bf16 inputs, 0 = f32 inputs
__device__ int g_mask_mode;    // 0=i32, 1=u8, 2=f32, 3=bf16
__device__ __align__(16) short g_w1p[32 * 64];    // [oc][k=tap*16+ic], pad0
__device__ __align__(16) short g_w2p[64 * 96];    // [oc][k=tap*32+ic]
__device__ __align__(16) short g_w3p[128 * 192];  // [oc][k=tap*64+ic]
__device__ __align__(16) float g_b1[32];
__device__ __align__(16) float g_b2[64];
__device__ __align__(16) float g_b3[128];
__device__ __align__(16) float g_wqk[4 * 128];    // per-head q-folded Wk
__device__ __align__(16) float g_qb[4];           // per-head q.bk

template <int DT>
__device__ __forceinline__ float ldf(const void* p, long i) {
    if (DT) return __bfloat162float(((const bf16*)p)[i]);
    return ((const float*)p)[i];
}
template <int DT>
__device__ __forceinline__ void stf(void* p, long i, float v) {
    if (DT) ((bf16*)p)[i] = __float2bfloat16(v);
    else    ((float*)p)[i] = v;
}
__device__ __forceinline__ unsigned short f2bu(float x) {
    bf16 b = __float2bfloat16(x);
    union { bf16 b; unsigned short u; } cv; cv.b = b; return cv.u;
}
__device__ __forceinline__ float bu2f(unsigned short u) {
    union { unsigned int i; float f; } cv; cv.i = ((unsigned int)u) << 16; return cv.f;
}
template <int DT>
__device__ __forceinline__ float2 ldf2(const void* p, long i) {  // i even
    if (DT) {
        unsigned int u = *(const unsigned int*)((const bf16*)p + i);
        return make_float2(bu2f((unsigned short)(u & 0xffffu)),
                           bu2f((unsigned short)(u >> 16)));
    }
    return *(const float2*)((const float*)p + i);
}
__device__ __forceinline__ bool mask_at(const void* p, long i, int mode) {
    if (mode == 0) return ((const int*)p)[i] != 0;
    if (mode == 1) return ((const unsigned char*)p)[i] != 0;
    if (mode == 2) return ((const float*)p)[i] != 0.f;
    return (((const unsigned short*)p)[i] & 0x7fff) != 0;
}

// 64-element row-dot: sum_i W[off+i] * y[i], vectorized 16B loads
template <int DT>
__device__ __forceinline__ float rowdot64(const void* W, long off, const float* y) {
    float acc = 0.f;
    if (DT) {
        const unsigned short* wr = (const unsigned short*)W + off;
#pragma unroll
        for (int i = 0; i < 8; i++) {
            uint4 w = *(const uint4*)(wr + i * 8);
            acc = fmaf(bu2f((unsigned short)(w.x & 0xffffu)), y[i * 8 + 0], acc);
            acc = fmaf(bu2f((unsigned short)(w.x >> 16)),     y[i * 8 + 1], acc);
            acc = fmaf(bu2f((unsigned short)(w.y & 0xffffu)), y[i * 8 + 2], acc);
            acc = fmaf(bu2f((unsigned short)(w.y >> 16)),     y[i * 8 + 3], acc);
            acc = fmaf(bu2f((unsigned short)(w.z & 0xffffu)), y[i * 8 + 4], acc);
            acc = fmaf(bu2f((unsigned short)(w.z >> 16)),     y[i * 8 + 5], acc);
            acc = fmaf(bu2f((unsigned short)(w.w & 0xffffu)), y[i * 8 + 6], acc);
            acc = fmaf(bu2f((unsigned short)(w.w >> 16)),     y[i * 8 + 7], acc);
        }
    } else {
        const float* wr = (const float*)W + off;
#pragma unroll
        for (int i = 0; i < 16; i++) {
            float4 w = *(const float4*)(wr + i * 4);
            acc = fmaf(w.x, y[i * 4 + 0], acc);
            acc = fmaf(w.y, y[i * 4 + 1], acc);
            acc = fmaf(w.z, y[i * 4 + 2], acc);
            acc = fmaf(w.w, y[i * 4 + 3], acc);
        }
    }
    return acc;
}

// ---------------- weight pad/transpose/cast (grid-stride over 64 blocks) ----------------
template <int DT>
__device__ __forceinline__ void prep_body(const void* w1, const void* b1,
                                          const void* w2, const void* b2,
                                          const void* w3, const void* b3) {
    int tid = blockIdx.x * 256 + threadIdx.x;
    const int nt = 64 * 256;
    for (int i = tid; i < 32 * 64; i += nt) {
        int oc = i >> 6, k = i & 63, tap = k >> 4, ic = k & 15;
        float v = (tap < 3 && ic < 9) ? ldf<DT>(w1, oc * 27 + ic * 3 + tap) : 0.f;
        g_w1p[i] = (short)f2bu(v);
    }
    for (int i = tid; i < 64 * 96; i += nt) {
        int oc = i / 96, k = i % 96, tap = k >> 5, ic = k & 31;
        g_w2p[i] = (short)f2bu(ldf<DT>(w2, oc * 96 + ic * 3 + tap));
    }
    for (int i = tid; i < 128 * 192; i += nt) {
        int oc = i / 192, k = i % 192, tap = k >> 6, ic = k & 63;
        g_w3p[i] = (short)f2bu(ldf<DT>(w3, oc * 192 + ic * 3 + tap));
    }
    for (int i = tid; i < 32; i += nt) g_b1[i] = ldf<DT>(b1, i);
    for (int i = tid; i < 64; i += nt) g_b2[i] = ldf<DT>(b2, i);
    for (int i = tid; i < 128; i += nt) g_b3[i] = ldf<DT>(b3, i);
}

// block 64: q = query@Wq^T+bq, then fold through Wk: g_wqk[h][e], g_qb[h]
template <int DT>
__device__ __forceinline__ void qprep_body(const void* query, const void* ipw,
                                           const void* ipb, float* sq) {
    int tid = threadIdx.x;
    if (tid < 128) {
        float acc = ldf<DT>(ipb, tid);
        for (int e = 0; e < 128; e++)
            acc = fmaf(ldf<DT>(query, e), ldf<DT>(ipw, (long)tid * 128 + e), acc);
        sq[tid] = acc;
    }
    __syncthreads();
    int e = tid & 127, hb = tid >> 7;
    for (int h = hb; h < 4; h += 2) {
        float acc = 0.f;
#pragma unroll
        for (int j = 0; j < 32; j++)
            acc = fmaf(sq[h * 32 + j], ldf<DT>(ipw, (long)(128 + h * 32 + j) * 128 + e), acc);
        g_wqk[h * 128 + e] = acc;
    }
    if (tid < 4) {
        float acc = 0.f;
#pragma unroll
        for (int j = 0; j < 32; j++)
            acc = fmaf(sq[tid * 32 + j], ldf<DT>(ipb, 128 + tid * 32 + j), acc);
        g_qb[tid] = acc;
    }
}

// ---------------- launch A: per-block detect + prep + q-fold ----------------
__global__ __launch_bounds__(256) void prep_kernel(
    const unsigned int* __restrict__ pw, const unsigned char* __restrict__ m,
    const void* __restrict__ w1, const void* __restrict__ b1,
    const void* __restrict__ w2, const void* __restrict__ b2,
    const void* __restrict__ w3, const void* __restrict__ b3,
    const void* __restrict__ query, const void* __restrict__ ipw,
    const void* __restrict__ ipb) {
    __shared__ int cls[4];
    __shared__ int mv;
    __shared__ int good;
    __shared__ float sq[128];
    int tid = threadIdx.x;
    if (tid < 4) cls[tid] = 0;
    if (tid == 0) { mv = 0; good = 0; }
    __syncthreads();
    int g = 0;
    for (int i = tid; i < 1024; i += 256) {
        unsigned int w = pw[i];
        unsigned int h0 = w & 0xffffu, h1 = w >> 16;
        unsigned int e0 = (h0 >> 7) & 0xff, e1 = (h1 >> 7) & 0xff;
        if (h0 == 0 || (e0 >= 90 && e0 <= 160)) g++;
        if (h1 == 0 || (e1 >= 90 && e1 <= 160)) g++;
    }
    atomicAdd(&good, g);
    int l0 = 0, l1 = 0, l2 = 0, l3 = 0, lm = 0;
    for (int i = tid; i < 4096; i += 256) {
        int v = m[i];
        if (v) {
            switch (i & 3) { case 0: l0 = 1; break; case 1: l1 = 1; break;
                             case 2: l2 = 1; break; default: l3 = 1; }
            if (v > lm) lm = v;
        }
    }
    if (l0) atomicOr(&cls[0], 1);
    if (l1) atomicOr(&cls[1], 1);
    if (l2) atomicOr(&cls[2], 1);
    if (l3) atomicOr(&cls[3], 1);
    atomicMax(&mv, lm);
    __syncthreads();
    int dt = (good >= 1740) ? 1 : 0;
    int mode;
    if (!cls[1] && !cls[2] && !cls[3]) mode = 0;
    else if (!cls[0] && !cls[1])       mode = 2;
    else if (mv <= 1)                  mode = 1;
    else                               mode = 3;
    if (blockIdx.x == 0 && tid == 0) { g_dtype = dt; g_mask_mode = mode; }

    if (blockIdx.x < 64) {
        if (dt) prep_body<1>(w1, b1, w2, b2, w3, b3);
        else    prep_body<0>(w1, b1, w2, b2, w3, b3);
    } else {
        if (dt) qprep_body<1>(query, ipw, ipb, sq);
        else    qprep_body<0>(query, ipw, ipb, sq);
    }
}

// ---------------- stage 1 (round-1 verified): 16 agents/block, 4 waves ----------------
// LDS (shorts). Region A: feat [16][FEAT_AS], reused as h2. Region B: h1
// [16][H1_AS], reused as c3. Agent strides == +-4 banks (mod 32): lanes step
// the AGENT axis (ag = col) => 2-way bank aliasing (free, m136).
#define FEAT_RS 24     // rows t=0..21 (20/21 zero); 48 B
#define FEAT_AS 568    // 1136 B == -4 banks (mod 32)
#define H1_RS 40       // rows t=0..10 (10 zero); 80 B
#define H1_AS 440      // 880 B == -4 banks
#define H2_RS 72       // rows r=0..6 (0,6 zero); 144 B
#define H2_AS 504      // 1008 B == -4 banks
#define C3_AS 392      // 3*128 + 8 pad; 784 B == +4 banks
#define OFF_H1 9088    // shorts = 16*FEAT_AS
#define OFF_VALID 32256 // bytes = 18176 + 16*H1_AS*2
#define SMEM_BYTES 32320 // -> 32768 alloc => 5 blocks/CU

#define MFMA16(a, b, c) __builtin_amdgcn_mfma_f32_16x16x32_bf16((a), (b), (c), 0, 0, 0)

template <int DT>
__device__ __forceinline__ void stage1_body(
    const void* pos, const void* heading, const void* vel, const void* shp,
    const void* vmask, const int* category, const void* type_emb, void* out,
    char* smem, long agent0) {
    short* feat = (short*)smem;               // region A
    short* h1   = (short*)smem + OFF_H1;      // region B
    short* h2   = (short*)smem;               // region A reuse (feat dead after conv1)
    short* c3   = (short*)smem + OFF_H1;      // region B reuse (h1 dead after conv2)
    int* s_valid = (int*)(smem + OFF_VALID);

    const int tid = threadIdx.x;
    const int wave = tid >> 6, lane = tid & 63;
    const int col = lane & 15, quad = lane >> 4;
    const int mode = g_mask_mode;

    // ---- phase 0: valid init + h1 zero-pad row ----
    if (tid < 16) s_valid[tid] = 0;
    {
        unsigned int* h1u = (unsigned int*)h1;          // h1 row 10 zero
        h1u[(tid >> 4) * 220 + 200 + (tid & 15)] = 0;
    }
    __syncthreads();

    // ---- phase 1: feature build (bf16, [ag][t][ch16]) ----
    for (int idx = tid; idx < 16 * 22; idx += 256) {
        int ag = idx / 22, t = idx % 22;
        short* row = feat + ag * FEAT_AS + t * FEAT_RS;
        if (t >= 20) {
            *(uint4*)row = make_uint4(0, 0, 0, 0);
            *(uint4*)(row + 8) = make_uint4(0, 0, 0, 0);
            if (t == 20) {
                long base = (agent0 + ag) * TT + 20;
                if (mask_at(vmask, base, mode)) atomicOr(&s_valid[ag], 1);
            }
        } else {
            long base = (agent0 + ag) * TT + t;
            bool vmt = mask_at(vmask, base, mode);
            if (vmt) atomicOr(&s_valid[ag], 1);
            bool m2 = vmt && mask_at(vmask, base + 1, mode);
            float2 pa = ldf2<DT>(pos, base * 2), pb = ldf2<DT>(pos, base * 2 + 2);
            float2 va = ldf2<DT>(vel, base * 2), vb = ldf2<DT>(vel, base * 2 + 2);
            float hh0 = ldf<DT>(heading, base), hh1 = ldf<DT>(heading, base + 1);
            float2 sv = ldf2<DT>(shp, base * 2 + 2);
            float dh = m2 ? (hh1 - hh0) : 0.f;      // masked: cos=1, sin=0 (ref)
            float sn, cn;
            __sincosf(dh, &sn, &cn);
            unsigned int p0 = f2bu(m2 ? pb.x - pa.x : 0.f) | ((unsigned int)f2bu(m2 ? pb.y - pa.y : 0.f) << 16);
            unsigned int p1 = f2bu(m2 ? vb.x - va.x : 0.f) | ((unsigned int)f2bu(m2 ? vb.y - va.y : 0.f) << 16);
            unsigned int p2 = f2bu(cn) | ((unsigned int)f2bu(sn) << 16);
            unsigned int p3 = f2bu(sv.x) | ((unsigned int)f2bu(sv.y) << 16);
            unsigned int p4 = (unsigned int)f2bu(m2 ? 1.f : 0.f);
            *(uint4*)row = make_uint4(p0, p1, p2, p3);
            *(uint4*)(row + 8) = make_uint4(p4, 0, 0, 0);
        }
    }
    __syncthreads();

    // ---- conv1: M=32 (2 Mt), K=64, N=16ag x 10p => ag=col, p per-iter ----
    {
        int Mt = wave >> 1;
        int oc = Mt * 16 + col;
        s8v a0 = *(const s8v*)(g_w1p + oc * 64 + quad * 8);
        s8v a1 = *(const s8v*)(g_w1p + oc * 64 + 32 + quad * 8);
        int k0 = quad * 8, k1 = 32 + quad * 8;
        int tap0 = k0 >> 4, ic0 = k0 & 15;
        int tap1 = k1 >> 4, ic1 = k1 & 15;
        int ocr = Mt * 16 + quad * 4;
        f4v bia = *(const f4v*)(g_b1 + ocr);
        int ag = col;
        const short* agbase = feat + ag * FEAT_AS;
#pragma unroll
        for (int i = 0; i < 5; i++) {
            int p = (wave & 1) * 5 + i;
            const short* bb = agbase + 2 * p * FEAT_RS;
            s8v b0 = *(const s8v*)(bb + tap0 * FEAT_RS + ic0);
            s8v b1 = *(const s8v*)(bb + tap1 * FEAT_RS + ic1);
            f4v acc = {0.f, 0.f, 0.f, 0.f};
            acc = MFMA16(a0, b0, acc);
            acc = MFMA16(a1, b1, acc);
            unsigned int lo = f2bu(fmaxf(acc[0] + bia[0], 0.f)) | ((unsigned int)f2bu(fmaxf(acc[1] + bia[1], 0.f)) << 16);
            unsigned int hi = f2bu(fmaxf(acc[2] + bia[2], 0.f)) | ((unsigned int)f2bu(fmaxf(acc[3] + bia[3], 0.f)) << 16);
            *(uint2*)(h1 + ag * H1_AS + p * H1_RS + ocr) = make_uint2(lo, hi);
        }
    }
    __syncthreads();

    // ---- conv2: M=64 (4 Mt), K=96, N=16ag x 5p => ag=col, p=Nt. Zero h2 pad
    //      rows 0 & 6 first (region A: feat dead; before the phase barrier) ----
    {
        unsigned int* h2u = (unsigned int*)h2;
        for (int i = tid; i < 1024; i += 256) {
            int a2 = i >> 6, r = (i >> 5) & 1, cc = i & 31;
            h2u[a2 * 252 + r * 216 + cc] = 0;
        }
        int Mt = wave;
        int oc = Mt * 16 + col;
        s8v a[3];
#pragma unroll
        for (int ks = 0; ks < 3; ks++)
            a[ks] = *(const s8v*)(g_w2p + oc * 96 + ks * 32 + quad * 8);
        int ocr = Mt * 16 + quad * 4;
        f4v bia = *(const f4v*)(g_b2 + ocr);
        int ag = col;
#pragma unroll
        for (int p = 0; p < 5; p++) {
            f4v acc = {0.f, 0.f, 0.f, 0.f};
#pragma unroll
            for (int ks = 0; ks < 3; ks++) {
                s8v b = *(const s8v*)(h1 + ag * H1_AS + (2 * p + ks) * H1_RS + quad * 8);
                acc = MFMA16(a[ks], b, acc);
            }
            unsigned int lo = f2bu(fmaxf(acc[0] + bia[0], 0.f)) | ((unsigned int)f2bu(fmaxf(acc[1] + bia[1], 0.f)) << 16);
            unsigned int hi = f2bu(fmaxf(acc[2] + bia[2], 0.f)) | ((unsigned int)f2bu(fmaxf(acc[3] + bia[3], 0.f)) << 16);
            *(uint2*)(h2 + ag * H2_AS + (p + 1) * H2_RS + ocr) = make_uint2(lo, hi);
        }
    }
    __syncthreads();

    // ---- conv3: M=128 (8 Mt, 2/wave), K=192 (6 slices), N=16ag x 3p ----
#pragma unroll
    for (int m2 = 0; m2 < 2; m2++) {
        int Mt = wave * 2 + m2;
        int oc = Mt * 16 + col;
        s8v a[6];
#pragma unroll
        for (int ks = 0; ks < 6; ks++)
            a[ks] = *(const s8v*)(g_w3p + oc * 192 + ks * 32 + quad * 8);
        int ocr = Mt * 16 + quad * 4;
        f4v bia = *(const f4v*)(g_b3 + ocr);
        int ag = col;
#pragma unroll
        for (int p = 0; p < 3; p++) {
            f4v acc = {0.f, 0.f, 0.f, 0.f};
#pragma unroll
            for (int ks = 0; ks < 6; ks++) {
                int kg = ks * 32 + quad * 8;
                int tap = kg >> 6, ic = kg & 63;
                s8v b = *(const s8v*)(h2 + ag * H2_AS + (2 * p + tap) * H2_RS + ic);
                acc = MFMA16(a[ks], b, acc);
            }
            unsigned int lo = f2bu(fmaxf(acc[0] + bia[0], 0.f)) | ((unsigned int)f2bu(fmaxf(acc[1] + bia[1], 0.f)) << 16);
            unsigned int hi = f2bu(fmaxf(acc[2] + bia[2], 0.f)) | ((unsigned int)f2bu(fmaxf(acc[3] + bia[3], 0.f)) << 16);
            *(uint2*)(c3 + ag * C3_AS + p * 128 + ocr) = make_uint2(lo, hi);
        }
    }
    __syncthreads();

    // ---- epilogue: mean over 3 p, valid mask, + type_emb; skip agent-0 rows ----
    {
        int ag = tid >> 4;
        int ocg = (tid & 15) * 8;
        const short* cb = c3 + ag * C3_AS;
        s8v x0 = *(const s8v*)(cb + ocg);
        s8v x1 = *(const s8v*)(cb + 128 + ocg);
        s8v x2 = *(const s8v*)(cb + 256 + ocg);
        int valid = s_valid[ag];
        long agl = agent0 + ag;
        bool skip = ((agl & (AAG - 1)) == 0);   // stage2 owns out[b][0]
        int cat = category[agl];
        float vals[8];
#pragma unroll
        for (int j = 0; j < 8; j++) {
            float m = (bu2f((unsigned short)x0[j]) + bu2f((unsigned short)x1[j]) +
                       bu2f((unsigned short)x2[j])) * (1.f / 3.f);
            vals[j] = valid ? m : 0.f;
        }
        if (!skip) {
            if (DT) {
                s8v te = *(const s8v*)((const bf16*)type_emb + (long)cat * 128 + ocg);
                s8v o;
#pragma unroll
                for (int j = 0; j < 8; j++)
                    o[j] = (short)f2bu(vals[j] + bu2f((unsigned short)te[j]));
                *(s8v*)((bf16*)out + agl * 128 + ocg) = o;
            } else {
                const float4* tep = (const float4*)((const float*)type_emb + (long)cat * 128 + ocg);
                float4 t0 = tep[0], t1 = tep[1];
                float4 o0 = make_float4(vals[0] + t0.x, vals[1] + t0.y, vals[2] + t0.z, vals[3] + t0.w);
                float4 o1 = make_float4(vals[4] + t1.x, vals[5] + t1.y, vals[6] + t1.z, vals[7] + t1.w);
                float4* op = (float4*)((float*)out + agl * 128 + ocg);
                op[0] = o0; op[1] = o1;
            }
        }
    }
}

// ---------------- stage 2 (256 threads): ego cross-attention, writes out[b][0] ----------------
// q/k pre-folded (g_wqk, g_qb). softmax weights sum to 1 =>
// o[d] = bv[d] + sum_e y_{h(d)}[e] * Wv[d][e], y_h[e] = sum_s att[h,s]*xe[s,e].
template <int DT>
__device__ __forceinline__ void stage2_body(
    const void* cs, const int* category,
    const void* se_w, const void* se_b, const void* pe,
    const void* ipw, const void* ipb, const void* opw, const void* opb,
    const void* type_emb, void* out, char* smem) {
    const int b = blockIdx.x;
    const int tid = threadIdx.x;
    const int d = tid & 127, half = tid >> 7;

    float* s_xe  = (float*)smem;        // [6][128]
    float* s_y   = s_xe + 768;          // [4][128]
    float* s_sc  = s_y + 512;           // [4*6] (+pad)
    float* s_att = s_sc + 32;           // [4*6] (+pad)
    float* s_o   = s_att + 32;          // [128]
    float* s_par = s_o + 128;           // [2][128]

    for (int idx = tid; idx < 768; idx += 256) {
        int s = idx >> 7, dd = idx & 127;
        float ego = ldf<DT>(cs, b * 6 + s);
        s_xe[idx] = fmaf(ego, ldf<DT>(se_w, s * 128 + dd),
                         ldf<DT>(se_b, s * 128 + dd) + ldf<DT>(pe, s * 128 + dd));
    }
    __syncthreads();

    // scores: 24 (h,s) pairs x 4 lanes each, 32-e partials + width-4 reduce
    if (tid < 96) {
        int g = tid >> 2, lig = tid & 3;
        int h = g / 6, s = g - h * 6;
        const float* xr = s_xe + s * 128 + lig * 32;
        const float* wr = g_wqk + h * 128 + lig * 32;
        float t = 0.f;
#pragma unroll
        for (int e = 0; e < 32; e++) t = fmaf(xr[e], wr[e], t);
        t += __shfl_xor(t, 1, 4);
        t += __shfl_xor(t, 2, 4);
        if (lig == 0) s_sc[g] = (t + g_qb[h]) * 0.17677669529663687f;
    }
    __syncthreads();

    if (tid < 4) {
        float mx = -1e30f;
#pragma unroll
        for (int s = 0; s < 6; s++) mx = fmaxf(mx, s_sc[tid * 6 + s]);
        float sum = 0.f, ex[6];
#pragma unroll
        for (int s = 0; s < 6; s++) { ex[s] = expf(s_sc[tid * 6 + s] - mx); sum += ex[s]; }
        float inv = 1.f / sum;
#pragma unroll
        for (int s = 0; s < 6; s++) s_att[tid * 6 + s] = ex[s] * inv;
    }
    __syncthreads();

    for (int idx = tid; idx < 512; idx += 256) {
        int h = idx >> 7, e = idx & 127;
        float y = 0.f;
#pragma unroll
        for (int s = 0; s < 6; s++) y = fmaf(s_att[h * 6 + s], s_xe[s * 128 + e], y);
        s_y[idx] = y;
    }
    __syncthreads();

    {   // o[d] partial over 64 e (Wv row = ipw row 256+d)
        int h = d >> 5;
        const float* yr = s_y + h * 128 + half * 64;
        s_par[half * 128 + d] = rowdot64<DT>(ipw, (long)(256 + d) * 128 + half * 64, yr);
    }
    __syncthreads();
    if (half == 0) s_o[d] = s_par[d] + s_par[128 + d] + ldf<DT>(ipb, 256 + d);
    __syncthreads();

    {   // x_ego[d] partial over 64 e (Wo row d)
        const float* orr = s_o + half * 64;
        s_par[half * 128 + d] = rowdot64<DT>(opw, (long)d * 128 + half * 64, orr);
    }
    __syncthreads();
    if (half == 0) {
        float x = s_par[d] + s_par[128 + d] + ldf<DT>(opb, d);
        int cat = category[(long)b * AAG];
        stf<DT>(out, (long)b * AAG * 128 + d, x + ldf<DT>(type_emb, cat * 128 + d));
    }
}

// ---------------- launch B: fused stage2 (blocks<256) + stage1 ----------------
__global__ __launch_bounds__(256) void fused_kernel(
    const void* __restrict__ pos, const void* __restrict__ heading,
    const void* __restrict__ vel, const void* __restrict__ shp,
    const void* __restrict__ vmask, const int* __restrict__ category,
    const void* __restrict__ type_emb, void* __restrict__ out,
    const void* __restrict__ cs, const void* __restrict__ se_w,
    const void* __restrict__ se_b, const void* __restrict__ pe,
    const void* __restrict__ ipw, const void* __restrict__ ipb,
    const void* __restrict__ opw, const void* __restrict__ opb) {
    __shared__ __align__(16) char smem[SMEM_BYTES];
    if (blockIdx.x < BB) {
        if (g_dtype) stage2_body<1>(cs, category, se_w, se_b, pe, ipw, ipb, opw, opb, type_emb, out, smem);
        else         stage2_body<0>(cs, category, se_w, se_b, pe, ipw, ipb, opw, opb, type_emb, out, smem);
    } else {
        long agent0 = (long)(blockIdx.x - BB) * 16;
        if (g_dtype) stage1_body<1>(pos, heading, vel, shp, vmask, category, type_emb, out, smem, agent0);
        else         stage1_body<0>(pos, heading, vel, shp, vmask, category, type_emb, out, smem, agent0);
    }
}

extern "C" void kernel_launch(void* const* d_in, const int* in_sizes, int n_in,
                              void* d_out, int out_size, void* d_ws, size_t ws_size,
                              hipStream_t stream) {
    const void* position      = d_in[0];
    const void* heading       = d_in[1];
    const void* velocity      = d_in[2];
    const void* shape         = d_in[3];
    const void* current_state = d_in[4];
    const int*  category      = (const int*)d_in[5];
    const void* valid_mask    = d_in[6];
    const void* conv1_w = d_in[7];
    const void* conv1_b = d_in[8];
    const void* conv2_w = d_in[9];
    const void* conv2_b = d_in[10];
    const void* conv3_w = d_in[11];
    const void* conv3_b = d_in[12];
    const void* se_w    = d_in[13];
    const void* se_b    = d_in[14];
    const void* pos_embed = d_in[15];
    const void* query     = d_in[16];
    const void* in_proj_w = d_in[17];
    const void* in_proj_b = d_in[18];
    const void* out_proj_w = d_in[19];
    const void* out_proj_b = d_in[20];
    const void* type_emb   = d_in[21];

    hipLaunchKernelGGL(prep_kernel, dim3(65), dim3(256), 0, stream,
                       (const unsigned int*)position, (const unsigned char*)valid_mask,
                       conv1_w, conv1_b, conv2_w, conv2_b, conv3_w, conv3_b,
                       query, in_proj_w, in_proj_b);

    hipLaunchKernelGGL(fused_kernel, dim3(BB + NAG / 16), dim3(256), 0, stream,
                       position, heading, velocity, shape, valid_mask, category,
                       type_emb, d_out,
                       current_state, se_w, se_b, pos_embed,
                       in_proj_w, in_proj_b, out_proj_w, out_proj_b);
}